// Round 1
// baseline (97.278 us; speedup 1.0000x reference)
//
#include <hip/hip_runtime.h>

// 3-level separable 2D DWT, bior3.5, mode='periodization'.
// out[i] = sum_j f[j] * x[(2i+1-j) mod N] along each axis.
// Subband naming (pywt dwt2): aa=LO(rows)∘LO(cols), da=HI(rows)∘LO(cols),
// ad=LO(rows)∘HI(cols), dd=HI(rows)∘HI(cols); rows = axis -2 applied second.

#define OW 32
#define OH 8
#define IN_ROWS (2 * OH + 10)   // 26
#define IN_COLS (2 * OW + 10)   // 74
#define IN_COLS_P (IN_COLS + 2) // 76, pad to dodge bank conflicts on row stride

__global__ __launch_bounds__(256) void dwt2_level(
    const float* __restrict__ src, int N,
    float* __restrict__ aa, float* __restrict__ da,
    float* __restrict__ ad, float* __restrict__ dd)
{
    constexpr float SQ2 = 1.41421356237309504880f;
    // bior3.5 dec_lo (12 taps, symmetric) and dec_hi (4 nonzero taps).
    // constexpr so the fully-unrolled loops fold the zero taps of c_hi.
    constexpr float c_lo[12] = {
        -20.f * SQ2 / 2048.f,  60.f * SQ2 / 2048.f,   76.f * SQ2 / 2048.f,
        -388.f * SQ2 / 2048.f, -104.f * SQ2 / 2048.f, 1400.f * SQ2 / 2048.f,
        1400.f * SQ2 / 2048.f, -104.f * SQ2 / 2048.f, -388.f * SQ2 / 2048.f,
        76.f * SQ2 / 2048.f,   60.f * SQ2 / 2048.f,   -20.f * SQ2 / 2048.f };
    constexpr float c_hi[12] = {
        0.f, 0.f, 0.f, 0.f,
        -SQ2 / 8.f, 3.f * SQ2 / 8.f, -3.f * SQ2 / 8.f, SQ2 / 8.f,
        0.f, 0.f, 0.f, 0.f };

    const int h    = N >> 1;
    const int mask = N - 1;
    const int bc   = blockIdx.z;
    const int j0   = blockIdx.x * OW;  // output col base
    const int i0   = blockIdx.y * OH;  // output row base
    const int tid  = threadIdx.x;      // 0..255

    __shared__ float s_in[IN_ROWS][IN_COLS_P];  // 26 x 76 (7.9 KB)
    __shared__ float s_lo[IN_ROWS][OW + 1];     // 26 x 33 (3.4 KB)
    __shared__ float s_hi[IN_ROWS][OW + 1];     // 26 x 33 (3.4 KB)

    const float* img = src + (size_t)bc * N * N;

    // Phase 0: stage input tile. Global rows r0..r0+25, cols c0..c0+73 (wrapped).
    const int r0 = 2 * i0 - 10;
    const int c0 = 2 * j0 - 10;
    for (int t = tid; t < IN_ROWS * IN_COLS; t += 256) {
        int r = t / IN_COLS;
        int c = t - r * IN_COLS;
        int gr = (r0 + r) & mask;
        int gc = (c0 + c) & mask;
        s_in[r][c] = img[(size_t)gr * N + gc];
    }
    __syncthreads();

    // Phase 1: row pass (filter along width). 26 rows x 32 output cols.
    for (int t = tid; t < IN_ROWS * OW; t += 256) {
        int r = t >> 5;       // / OW
        int j = t & (OW - 1); // % OW
        // needed input col (local) = 2*j + 11 - jc
        const int base = 2 * j + 11;
        float lo = 0.f, hi = 0.f;
        #pragma unroll
        for (int jc = 0; jc < 12; ++jc) {
            float v = s_in[r][base - jc];
            lo += c_lo[jc] * v;
            hi += c_hi[jc] * v;
        }
        s_lo[r][j] = lo;
        s_hi[r][j] = hi;
    }
    __syncthreads();

    // Phase 2: column pass. Each thread owns output (i0+ty, j0+tx), 4 subbands.
    const int tx = tid & (OW - 1);
    const int ty = tid >> 5;
    float vaa = 0.f, vda = 0.f, vad = 0.f, vdd = 0.f;
    #pragma unroll
    for (int jr = 0; jr < 12; ++jr) {
        const int r = 2 * ty + 11 - jr;  // LDS row for global row 2*(i0+ty)+1-jr
        float l  = s_lo[r][tx];
        float hh = s_hi[r][tx];
        vaa += c_lo[jr] * l;
        vda += c_hi[jr] * l;
        vad += c_lo[jr] * hh;
        vdd += c_hi[jr] * hh;
    }
    const size_t o = (size_t)bc * h * h + (size_t)(i0 + ty) * h + (j0 + tx);
    aa[o] = vaa;
    da[o] = vda;
    ad[o] = vad;
    dd[o] = vdd;
}

extern "C" void kernel_launch(void* const* d_in, const int* in_sizes, int n_in,
                              void* d_out, int out_size, void* d_ws, size_t ws_size,
                              hipStream_t stream) {
    const float* x = (const float*)d_in[0];
    float* out = (float*)d_out;
    float* ws  = (float*)d_ws;

    // 24 independent N x N images (8 batch x 3 channels).
    const size_t s512 = (size_t)24 * 512 * 512;  // 6291456
    const size_t s256 = (size_t)24 * 256 * 256;  // 1572864
    const size_t s128 = (size_t)24 * 128 * 128;  //  393216

    // d_out layout (return order): a | h3(da,ad,dd) | h2(...) | h1(...)
    float* a_out = out;
    float* h3 = out + s128;
    float* h2 = out + 4 * s128;
    float* h1 = out + 4 * s128 + 3 * s256;

    // scratch: aa after level 1 (512^2) and level 2 (256^2)
    float* aa1 = ws;          // s512 floats
    float* aa2 = ws + s512;   // s256 floats
    (void)in_sizes; (void)n_in; (void)out_size; (void)ws_size;

    dim3 blk(256, 1, 1);
    // level 1: 1024 -> 512
    dwt2_level<<<dim3(512 / OW, 512 / OH, 24), blk, 0, stream>>>(
        x, 1024, aa1, h1, h1 + s512, h1 + 2 * s512);
    // level 2: 512 -> 256
    dwt2_level<<<dim3(256 / OW, 256 / OH, 24), blk, 0, stream>>>(
        aa1, 512, aa2, h2, h2 + s256, h2 + 2 * s256);
    // level 3: 256 -> 128
    dwt2_level<<<dim3(128 / OW, 128 / OH, 24), blk, 0, stream>>>(
        aa2, 256, a_out, h3, h3 + s128, h3 + 2 * s128);
}

// Round 2
// 93.104 us; speedup vs baseline: 1.0448x; 1.0448x over previous
//
#include <hip/hip_runtime.h>

// 3-level separable 2D DWT, bior3.5, mode='periodization'.
// out[i] = sum_j f[j] * x[(2i+1-j) mod N] along each axis.
// v2: float4 staging (interior fast path), pair-wise row pass via ds_read_b128,
//     transposed lo/hi tiles so the column pass reads b128, 2 output rows/thread,
//     32-bit index math throughout.

#define OW 32
#define OH 16
#define IN_ROWS (2 * OH + 10)   // 42 staged input rows
#define IN_COLS_P 80            // staged cols (76 needed; 80 loaded, /4 aligned)
#define TR_PAD 44               // transposed row pad (floats): 4-way-uniform banks, 16B aligned

__global__ __launch_bounds__(256, 6) void dwt2_level(
    const float* __restrict__ src, int N,
    float* __restrict__ aa, float* __restrict__ da,
    float* __restrict__ ad, float* __restrict__ dd)
{
    constexpr float SQ2 = 1.41421356237309504880f;
    constexpr float c_lo[12] = {
        -20.f * SQ2 / 2048.f,  60.f * SQ2 / 2048.f,   76.f * SQ2 / 2048.f,
        -388.f * SQ2 / 2048.f, -104.f * SQ2 / 2048.f, 1400.f * SQ2 / 2048.f,
        1400.f * SQ2 / 2048.f, -104.f * SQ2 / 2048.f, -388.f * SQ2 / 2048.f,
        76.f * SQ2 / 2048.f,   60.f * SQ2 / 2048.f,   -20.f * SQ2 / 2048.f };
    // dec_hi nonzero taps are jc = 4..7
    constexpr float c_hi4[4] = { -SQ2 / 8.f, 3.f * SQ2 / 8.f, -3.f * SQ2 / 8.f, SQ2 / 8.f };

    const int h    = N >> 1;
    const int mask = N - 1;
    const int bc   = blockIdx.z;
    const int j0   = blockIdx.x * OW;  // output col base
    const int i0   = blockIdx.y * OH;  // output row base
    const int tid  = threadIdx.x;      // 0..255

    __shared__ float s_in[IN_ROWS][IN_COLS_P];   // 42 x 80 (13.4 KB)
    __shared__ float s_loT[OW][TR_PAD];          // transposed: [out col][input row] (5.6 KB)
    __shared__ float s_hiT[OW][TR_PAD];          // (5.6 KB)  total 24.7 KB -> 6 blocks/CU

    const float* img = src + (unsigned)bc * (unsigned)(N * N);
    const int r0 = 2 * i0 - 10;   // first staged global row
    const int c0 = 2 * j0 - 12;   // first staged global col (16B aligned when >=0)

    const bool interior = (r0 >= 0) && (r0 + IN_ROWS <= N) &&
                          (c0 >= 0) && (c0 + IN_COLS_P <= N);

    // ---- Phase 0: stage input tile ----
    if (interior) {
        // 42 rows x 20 float4
        #pragma unroll
        for (int t = tid; t < IN_ROWS * 20; t += 256) {
            int r = t / 20;
            int q = t - r * 20;
            float4 v = *(const float4*)(img + (unsigned)((r0 + r) * N + c0 + 4 * q));
            *(float4*)&s_in[r][4 * q] = v;
        }
    } else {
        for (int t = tid; t < IN_ROWS * IN_COLS_P; t += 256) {
            int r = t / IN_COLS_P;
            int c = t - r * IN_COLS_P;
            int gr = (r0 + r) & mask;
            int gc = (c0 + c) & mask;
            s_in[r][c] = img[(unsigned)(gr * N + gc)];
        }
    }
    __syncthreads();

    // ---- Phase 1: row pass, one col-pair (2m, 2m+1) per task ----
    // output col j needs local cols [2j+2, 2j+13]; pair window [4m, 4m+15], 16B aligned.
    #pragma unroll
    for (int t = tid; t < IN_ROWS * 16; t += 256) {
        int r = t >> 4;
        int m = t & 15;
        const float* p = &s_in[r][4 * m];
        float v[16];
        *(float4*)&v[0]  = *(const float4*)&p[0];
        *(float4*)&v[4]  = *(const float4*)&p[4];
        *(float4*)&v[8]  = *(const float4*)&p[8];
        *(float4*)&v[12] = *(const float4*)&p[12];
        float lo0 = 0.f, lo1 = 0.f;
        #pragma unroll
        for (int jc = 0; jc < 12; ++jc) {
            lo0 += c_lo[jc] * v[13 - jc];
            lo1 += c_lo[jc] * v[15 - jc];
        }
        float hi0 = 0.f, hi1 = 0.f;
        #pragma unroll
        for (int k = 0; k < 4; ++k) {
            hi0 += c_hi4[k] * v[9 - k];
            hi1 += c_hi4[k] * v[11 - k];
        }
        s_loT[2 * m + 0][r] = lo0;
        s_loT[2 * m + 1][r] = lo1;
        s_hiT[2 * m + 0][r] = hi0;
        s_hiT[2 * m + 1][r] = hi1;
    }
    __syncthreads();

    // ---- Phase 2: column pass, 2 output rows per thread ----
    const int tx = tid & 31;      // output col within tile
    const int ty = tid >> 5;      // 0..7 -> output rows 2ty, 2ty+1
    float l[16], hh[16];
    {
        const float* pl = &s_loT[tx][4 * ty];
        const float* ph = &s_hiT[tx][4 * ty];
        *(float4*)&l[0]   = *(const float4*)&pl[0];
        *(float4*)&l[4]   = *(const float4*)&pl[4];
        *(float4*)&l[8]   = *(const float4*)&pl[8];
        *(float4*)&l[12]  = *(const float4*)&pl[12];
        *(float4*)&hh[0]  = *(const float4*)&ph[0];
        *(float4*)&hh[4]  = *(const float4*)&ph[4];
        *(float4*)&hh[8]  = *(const float4*)&ph[8];
        *(float4*)&hh[12] = *(const float4*)&ph[12];
    }
    // output row i = 2ty uses l[11-jr]; i = 2ty+1 uses l[13-jr]
    float vaa0 = 0.f, vad0 = 0.f, vaa1 = 0.f, vad1 = 0.f;
    #pragma unroll
    for (int jr = 0; jr < 12; ++jr) {
        vaa0 += c_lo[jr] * l[11 - jr];
        vaa1 += c_lo[jr] * l[13 - jr];
        vad0 += c_lo[jr] * hh[11 - jr];
        vad1 += c_lo[jr] * hh[13 - jr];
    }
    float vda0 = 0.f, vdd0 = 0.f, vda1 = 0.f, vdd1 = 0.f;
    #pragma unroll
    for (int k = 0; k < 4; ++k) {
        vda0 += c_hi4[k] * l[7 - k];
        vda1 += c_hi4[k] * l[9 - k];
        vdd0 += c_hi4[k] * hh[7 - k];
        vdd1 += c_hi4[k] * hh[9 - k];
    }
    const unsigned ob = (unsigned)((bc * h + i0 + 2 * ty) * h + j0 + tx);
    const unsigned oh = (unsigned)h;
    aa[ob] = vaa0;  aa[ob + oh] = vaa1;
    da[ob] = vda0;  da[ob + oh] = vda1;
    ad[ob] = vad0;  ad[ob + oh] = vad1;
    dd[ob] = vdd0;  dd[ob + oh] = vdd1;
}

extern "C" void kernel_launch(void* const* d_in, const int* in_sizes, int n_in,
                              void* d_out, int out_size, void* d_ws, size_t ws_size,
                              hipStream_t stream) {
    const float* x = (const float*)d_in[0];
    float* out = (float*)d_out;
    float* ws  = (float*)d_ws;

    // 24 independent N x N images (8 batch x 3 channels).
    const size_t s512 = (size_t)24 * 512 * 512;  // 6291456
    const size_t s256 = (size_t)24 * 256 * 256;  // 1572864
    const size_t s128 = (size_t)24 * 128 * 128;  //  393216

    // d_out layout (return order): a | h3(da,ad,dd) | h2(...) | h1(...)
    float* a_out = out;
    float* h3 = out + s128;
    float* h2 = out + 4 * s128;
    float* h1 = out + 4 * s128 + 3 * s256;

    // scratch: aa after level 1 (512^2) and level 2 (256^2)
    float* aa1 = ws;          // s512 floats
    float* aa2 = ws + s512;   // s256 floats
    (void)in_sizes; (void)n_in; (void)out_size; (void)ws_size;

    dim3 blk(256, 1, 1);
    // level 1: 1024 -> 512
    dwt2_level<<<dim3(512 / OW, 512 / OH, 24), blk, 0, stream>>>(
        x, 1024, aa1, h1, h1 + s512, h1 + 2 * s512);
    // level 2: 512 -> 256
    dwt2_level<<<dim3(256 / OW, 256 / OH, 24), blk, 0, stream>>>(
        aa1, 512, aa2, h2, h2 + s256, h2 + 2 * s256);
    // level 3: 256 -> 128
    dwt2_level<<<dim3(128 / OW, 128 / OH, 24), blk, 0, stream>>>(
        aa2, 256, a_out, h3, h3 + s128, h3 + 2 * s128);
}